// Round 11
// baseline (316.668 us; speedup 1.0000x reference)
//
#include <hip/hip_runtime.h>
#include <limits.h>
#include <math.h>

#define GRID 64
#define NUM_VOXELS (GRID * GRID * GRID)   // 262144
#define KSLOTS 16
#define CAP 32                            // per-voxel scratch capacity
#define FEAT 29
#define PIDBITS 0x1FFFFFu                 // 21 bits: supports n < 2^21 points

typedef float f32x4 __attribute__((ext_vector_type(4)));
typedef unsigned long long u64;

// Pass 1: scatter (key, payload) into per-voxel 32B entries.
//  key = conf_bits(32) << 32 | (~pid & 0x1FFFFF) << 11   [bits 0..10 zero]
//  payload = {x, y, z, desc_conf}  at entry offset 16 (16B-aligned).
// conf >= 0 so conf_bits is monotonic; MAX key == (conf desc, pid asc) —
// the reference's stable double-sort order, independent of atomic order.
// Binning: XLA folds (p-MIN)/0.02 -> (p-MIN)*50.0f exactly; must use the
// multiply (NOT an IEEE divide) to match floor() at voxel boundaries.
__global__ __launch_bounds__(256) void scatter_kernel(
    const float* __restrict__ pts, const float* __restrict__ conf,
    const float* __restrict__ desc_conf, int n,
    int* __restrict__ cnt, u64* __restrict__ buf) {
    int i = blockIdx.x * blockDim.x + threadIdx.x;
    if (i >= n) return;
    const float minc = (float)(-(64.0 * 0.02) / 2.0);  // -0.63999998569488525f
    const float rinv = 50.0f;                          // fold(1/0.02f) == 50.0f
    float x = pts[(size_t)i * 3 + 0];
    float y = pts[(size_t)i * 3 + 1];
    float z = pts[(size_t)i * 3 + 2];
    int ix = (int)floorf((x - minc) * rinv);
    int iy = (int)floorf((y - minc) * rinv);
    int iz = (int)floorf((z - minc) * rinv);
    if ((unsigned)ix >= GRID || (unsigned)iy >= GRID || (unsigned)iz >= GRID) return;
    int v = ix * (GRID * GRID) + iy * GRID + iz;
    int pos = atomicAdd(&cnt[v], 1);
    if (pos < CAP) {
        unsigned int cb = __float_as_uint(conf[i]);
        unsigned int lo = ((~(unsigned)i) & PIDBITS) << 11;
        u64* e = buf + ((size_t)v * CAP + pos) * 4;   // entry = 4 u64 = 32 B
        e[0] = ((u64)cb << 32) | lo;
        f32x4 pl = {x, y, z, desc_conf[i]};
        *(f32x4*)(e + 2) = pl;
    }
}

// Pass 2: one THREAD per voxel. Scan keys (OR-ing scan index j into the
// free low 5 bits), top-16 via unrolled compare-swap insertion, then pull
// each winner's payload from its entry (L1-hit: lines already fetched).
// Emits out_idx + stagedA(x,y,z,conf) + stagedB(desc_conf), all coalesced.
__global__ __launch_bounds__(256) void select_kernel(
    const int* __restrict__ cnt, const u64* __restrict__ buf,
    float* __restrict__ out_idx, f32x4* __restrict__ stagedA,
    float* __restrict__ stagedB) {
    int v = blockIdx.x * blockDim.x + threadIdx.x;
    if (v >= NUM_VOXELS) return;
    u64 top[KSLOTS];
    #pragma unroll
    for (int s = 0; s < KSLOTS; ++s) top[s] = 0ULL;
    int n = cnt[v];
    if (n > CAP) n = CAP;
    const u64* row = buf + (size_t)v * CAP * 4;
    for (int j = 0; j < n; ++j) {
        u64 key = row[(size_t)j * 4] | (unsigned)j;   // bits 0..4 free
        #pragma unroll
        for (int s = 0; s < KSLOTS; ++s) {
            u64 hi = key > top[s] ? key : top[s];
            u64 lo = key > top[s] ? top[s] : key;
            top[s] = hi;
            key    = lo;
        }
    }
    float* o  = out_idx + (size_t)v * KSLOTS;
    f32x4* sa = stagedA + (size_t)v * KSLOTS;
    float* sb = stagedB + (size_t)v * KSLOTS;
    #pragma unroll
    for (int s = 0; s < KSLOTS; ++s) {
        u64 a = top[s];
        float pidf = -1.0f;
        f32x4 pl = {0.0f, 0.0f, 0.0f, 0.0f};
        float dc = 0.0f;
        if (a != 0ULL) {
            int j = (int)(a & 31u);
            f32x4 p = *(const f32x4*)(row + (size_t)j * 4 + 2);
            int pid = (int)(PIDBITS & ~(unsigned)(a >> 11));
            pidf = (float)pid;                               // exact: pid < 2^21
            pl.x = p.x; pl.y = p.y; pl.z = p.z;
            pl.w = __uint_as_float((unsigned)(a >> 32));     // exact conf bits
            dc = p.w;
        }
        o[s]  = pidf;
        sa[s] = pl;
        sb[s] = dc;
    }
}

// Pass 3: feature gather, thread-per-slot. ONLY desc is a random fetch;
// pts/conf/desc_conf come from the coalesced staged arrays. LDS staging,
// NT streaming stores for the 486MB output.
__global__ __launch_bounds__(256) void gather_kernel(
    const f32x4* __restrict__ stagedA, const float* __restrict__ stagedB,
    const float* __restrict__ desc,
    const float* __restrict__ out_idx, float* __restrict__ out_feat) {
    const int t = threadIdx.x;
    const size_t slot0 = (size_t)blockIdx.x * 256;
    const size_t slot  = slot0 + t;
    __shared__ __align__(16) float st[256 * FEAT];   // 29696 B
    int pid = (int)out_idx[slot];
    f32x4 a = stagedA[slot];          // zeros for empty slots
    float dc = stagedB[slot];
    float f[FEAT];
    #pragma unroll
    for (int e = 0; e < FEAT; ++e) f[e] = 0.0f;
    f[0] = a.x; f[1] = a.y; f[2] = a.z; f[3] = a.w; f[28] = dc;
    if (pid >= 0) {
        const f32x4* d4 = (const f32x4*)(desc) + (size_t)pid * 6;  // 96B rows
        #pragma unroll
        for (int q = 0; q < 6; ++q) {
            f32x4 d = d4[q];
            f[4 + q * 4 + 0] = d.x; f[4 + q * 4 + 1] = d.y;
            f[4 + q * 4 + 2] = d.z; f[4 + q * 4 + 3] = d.w;
        }
    }
    #pragma unroll
    for (int e = 0; e < FEAT; ++e) st[t * FEAT + e] = f[e];
    __syncthreads();
    f32x4* dst = (f32x4*)(out_feat + slot0 * FEAT);
    const f32x4* src = (const f32x4*)st;
    #pragma unroll
    for (int k = t; k < 256 * FEAT / 4; k += 256)
        __builtin_nontemporal_store(src[k], &dst[k]);
}

// ---- Fallback (d_ws too small or n >= 2^21): round-8/10 proven kernels ----
__global__ __launch_bounds__(256) void scatter_kernel_nf(
    const float* __restrict__ pts, const float* __restrict__ conf, int n,
    int* __restrict__ cnt, u64* __restrict__ buf) {
    int i = blockIdx.x * blockDim.x + threadIdx.x;
    if (i >= n) return;
    const float minc = (float)(-(64.0 * 0.02) / 2.0);
    const float rinv = 50.0f;
    float x = pts[(size_t)i * 3 + 0];
    float y = pts[(size_t)i * 3 + 1];
    float z = pts[(size_t)i * 3 + 2];
    int ix = (int)floorf((x - minc) * rinv);
    int iy = (int)floorf((y - minc) * rinv);
    int iz = (int)floorf((z - minc) * rinv);
    if ((unsigned)ix >= GRID || (unsigned)iy >= GRID || (unsigned)iz >= GRID) return;
    int v = ix * (GRID * GRID) + iy * GRID + iz;
    int pos = atomicAdd(&cnt[v], 1);
    if (pos < CAP) {
        unsigned int cb = __float_as_uint(conf[i]);
        buf[(size_t)v * CAP + pos] = ((u64)cb << 32) | (unsigned int)(~i);
    }
}

__global__ __launch_bounds__(256) void select_kernel_nf(
    const int* __restrict__ cnt, const u64* __restrict__ buf,
    float* __restrict__ out_idx) {
    int v = blockIdx.x * blockDim.x + threadIdx.x;
    if (v >= NUM_VOXELS) return;
    u64 top[KSLOTS];
    #pragma unroll
    for (int s = 0; s < KSLOTS; ++s) top[s] = 0ULL;
    int n = cnt[v];
    if (n > CAP) n = CAP;
    const u64* row = buf + (size_t)v * CAP;
    for (int j = 0; j < n; ++j) {
        u64 key = row[j];
        #pragma unroll
        for (int s = 0; s < KSLOTS; ++s) {
            u64 hi = key > top[s] ? key : top[s];
            u64 lo = key > top[s] ? top[s] : key;
            top[s] = hi;
            key    = lo;
        }
    }
    float* o = out_idx + (size_t)v * KSLOTS;
    #pragma unroll
    for (int s = 0; s < KSLOTS; ++s) {
        u64 k = top[s];
        o[s] = (float)((k != 0ULL) ? (int)(~(unsigned int)k) : -1);
    }
}

__global__ __launch_bounds__(256) void gather_kernel_nf(
    const float* __restrict__ pts, const float* __restrict__ conf,
    const float* __restrict__ desc, const float* __restrict__ desc_conf,
    const float* __restrict__ out_idx, float* __restrict__ out_feat) {
    const int t = threadIdx.x;
    const size_t slot0 = (size_t)blockIdx.x * 256;
    const size_t slot  = slot0 + t;
    __shared__ __align__(16) float st[256 * FEAT];
    int pid = (int)out_idx[slot];
    float f[FEAT];
    #pragma unroll
    for (int e = 0; e < FEAT; ++e) f[e] = 0.0f;
    if (pid >= 0) {
        f[0] = pts[(size_t)pid * 3 + 0];
        f[1] = pts[(size_t)pid * 3 + 1];
        f[2] = pts[(size_t)pid * 3 + 2];
        f[3] = conf[pid];
        const f32x4* d4 = (const f32x4*)(desc) + (size_t)pid * 6;
        #pragma unroll
        for (int q = 0; q < 6; ++q) {
            f32x4 d = d4[q];
            f[4 + q * 4 + 0] = d.x; f[4 + q * 4 + 1] = d.y;
            f[4 + q * 4 + 2] = d.z; f[4 + q * 4 + 3] = d.w;
        }
        f[28] = desc_conf[pid];
    }
    #pragma unroll
    for (int e = 0; e < FEAT; ++e) st[t * FEAT + e] = f[e];
    __syncthreads();
    f32x4* dst = (f32x4*)(out_feat + slot0 * FEAT);
    const f32x4* src = (const f32x4*)st;
    #pragma unroll
    for (int k = t; k < 256 * FEAT / 4; k += 256)
        __builtin_nontemporal_store(src[k], &dst[k]);
}

extern "C" void kernel_launch(void* const* d_in, const int* in_sizes, int n_in,
                              void* d_out, int out_size, void* d_ws, size_t ws_size,
                              hipStream_t stream) {
    const float* pts       = (const float*)d_in[0];
    const float* conf      = (const float*)d_in[1];
    const float* desc      = (const float*)d_in[2];
    const float* desc_conf = (const float*)d_in[3];
    const int n = in_sizes[1];  // conf is (N,)

    float* out_idx  = (float*)d_out;                         // (V,16) as float
    float* out_feat = out_idx + (size_t)NUM_VOXELS * KSLOTS; // (V,16,29)

    const size_t sz_cnt = (size_t)NUM_VOXELS * 4;            // 1 MB
    const size_t sz_buf = (size_t)NUM_VOXELS * CAP * 32;     // 256 MB (32B entries)
    const size_t sz_sa  = (size_t)NUM_VOXELS * KSLOTS * 16;  // 67 MB
    const size_t sz_sb  = (size_t)NUM_VOXELS * KSLOTS * 4;   // 16 MB

    if (ws_size >= sz_cnt + sz_buf + sz_sa + sz_sb && (unsigned)n <= PIDBITS) {
        int* cnt = (int*)d_ws;
        u64* buf = (u64*)((char*)d_ws + sz_cnt);
        f32x4* stagedA = (f32x4*)((char*)d_ws + sz_cnt + sz_buf);
        float* stagedB = (float*)((char*)d_ws + sz_cnt + sz_buf + sz_sa);
        (void)hipMemsetAsync(cnt, 0, sz_cnt, stream);
        scatter_kernel<<<(n + 255) / 256, 256, 0, stream>>>(
            pts, conf, desc_conf, n, cnt, buf);
        select_kernel<<<NUM_VOXELS / 256, 256, 0, stream>>>(
            cnt, buf, out_idx, stagedA, stagedB);
        gather_kernel<<<(NUM_VOXELS * KSLOTS) / 256, 256, 0, stream>>>(
            stagedA, stagedB, desc, out_idx, out_feat);
    } else {
        // Fallback: 8B keys, scratch at head of X region (rewritten by gather).
        int* cnt = (int*)out_feat;
        u64* buf = (u64*)(out_feat + NUM_VOXELS);
        (void)hipMemsetAsync(cnt, 0, sz_cnt, stream);
        scatter_kernel_nf<<<(n + 255) / 256, 256, 0, stream>>>(pts, conf, n, cnt, buf);
        select_kernel_nf<<<NUM_VOXELS / 256, 256, 0, stream>>>(cnt, buf, out_idx);
        gather_kernel_nf<<<(NUM_VOXELS * KSLOTS) / 256, 256, 0, stream>>>(
            pts, conf, desc, desc_conf, out_idx, out_feat);
    }
}

// Round 12
// 227.027 us; speedup vs baseline: 1.3948x; 1.3948x over previous
//
#include <hip/hip_runtime.h>
#include <limits.h>
#include <math.h>

#define GRID 64
#define NUM_VOXELS (GRID * GRID * GRID)   // 262144
#define KSLOTS 16
#define CAP 32                            // per-voxel scratch capacity
#define FEAT 29

typedef float f32x4 __attribute__((ext_vector_type(4)));

// Pass 1: scatter packed (conf,pid) keys into per-voxel lists (round-8 form:
// 1 point/thread — 4x batching regressed in round 9 by cutting wave count).
// Key = (conf_bits << 32) | ~pid. conf >= 0 so conf_bits is monotonic in
// value; MAX key == (conf desc, pid asc) — the reference's stable double-sort
// order, deterministic regardless of atomic arrival order.
// Binning: XLA folds (p - MIN)/0.02 -> (p - MIN) * 50.0f exactly; must use
// the multiply (NOT an IEEE divide) to match floor() at voxel boundaries.
__global__ __launch_bounds__(256) void scatter_kernel(
    const float* __restrict__ pts, const float* __restrict__ conf, int n,
    int* __restrict__ cnt, unsigned long long* __restrict__ buf) {
    int i = blockIdx.x * blockDim.x + threadIdx.x;
    if (i >= n) return;
    const float minc = (float)(-(64.0 * 0.02) / 2.0);  // -0.63999998569488525f
    const float rinv = 50.0f;                          // fold(1/0.02f) == 50.0f
    float x = pts[(size_t)i * 3 + 0];
    float y = pts[(size_t)i * 3 + 1];
    float z = pts[(size_t)i * 3 + 2];
    int ix = (int)floorf((x - minc) * rinv);
    int iy = (int)floorf((y - minc) * rinv);
    int iz = (int)floorf((z - minc) * rinv);
    if ((unsigned)ix >= GRID || (unsigned)iy >= GRID || (unsigned)iz >= GRID) return;
    int v = ix * (GRID * GRID) + iy * GRID + iz;
    int pos = atomicAdd(&cnt[v], 1);
    if (pos < CAP) {
        unsigned int cb = __float_as_uint(conf[i]);
        unsigned long long key =
            ((unsigned long long)cb << 32) | (unsigned int)(~i);
        buf[(size_t)v * CAP + pos] = key;
    }
}

// Pass 2: one THREAD per voxel. Top-16 by key via unrolled 16-deep
// compare-swap insertion; empty sentinel 0. Also stages each slot's conf
// (recovered EXACTLY from the key's high 32 bits) into stagedC so gather
// never needs the random conf[pid] line fetch.
__global__ __launch_bounds__(256) void select_kernel(
    const int* __restrict__ cnt, const unsigned long long* __restrict__ buf,
    float* __restrict__ out_idx, float* __restrict__ stagedC) {
    int v = blockIdx.x * blockDim.x + threadIdx.x;
    if (v >= NUM_VOXELS) return;
    unsigned long long top[KSLOTS];
    #pragma unroll
    for (int s = 0; s < KSLOTS; ++s) top[s] = 0ULL;
    int n = cnt[v];
    if (n > CAP) n = CAP;
    const unsigned long long* row = buf + (size_t)v * CAP;
    for (int j = 0; j < n; ++j) {
        unsigned long long key = row[j];
        #pragma unroll
        for (int s = 0; s < KSLOTS; ++s) {
            unsigned long long hi = key > top[s] ? key : top[s];
            unsigned long long lo = key > top[s] ? top[s] : key;
            top[s] = hi;
            key    = lo;
        }
    }
    float* o = out_idx + (size_t)v * KSLOTS;
    float* c = stagedC + (size_t)v * KSLOTS;
    #pragma unroll
    for (int s = 0; s < KSLOTS; ++s) {
        unsigned long long k = top[s];
        o[s] = (float)((k != 0ULL) ? (int)(~(unsigned int)k) : -1);
        c[s] = __uint_as_float((unsigned int)(k >> 32));  // exact conf bits; 0.0 if empty
    }
}

// Pass 3: feature gather, thread-per-slot. Cached vector loads (desc via
// 6x 16B), conf from stagedC (coalesced), LDS staging, NT streaming stores.
__global__ __launch_bounds__(256) void gather_kernel(
    const float* __restrict__ pts, const float* __restrict__ stagedC,
    const float* __restrict__ desc, const float* __restrict__ desc_conf,
    const float* __restrict__ out_idx, float* __restrict__ out_feat) {
    const int t = threadIdx.x;
    const size_t slot0 = (size_t)blockIdx.x * 256;
    const size_t slot  = slot0 + t;
    __shared__ __align__(16) float st[256 * FEAT];   // 29696 B
    int pid = (int)out_idx[slot];
    float f[FEAT];
    #pragma unroll
    for (int e = 0; e < FEAT; ++e) f[e] = 0.0f;
    if (pid >= 0) {
        f[0] = pts[(size_t)pid * 3 + 0];
        f[1] = pts[(size_t)pid * 3 + 1];
        f[2] = pts[(size_t)pid * 3 + 2];
        f[3] = stagedC[slot];                        // exact conf via key bits
        const f32x4* d4 = (const f32x4*)(desc) + (size_t)pid * 6;  // 96B rows
        #pragma unroll
        for (int q = 0; q < 6; ++q) {
            f32x4 d = d4[q];
            f[4 + q * 4 + 0] = d.x; f[4 + q * 4 + 1] = d.y;
            f[4 + q * 4 + 2] = d.z; f[4 + q * 4 + 3] = d.w;
        }
        f[28] = desc_conf[pid];
    }
    #pragma unroll
    for (int e = 0; e < FEAT; ++e) st[t * FEAT + e] = f[e];
    __syncthreads();
    f32x4* dst = (f32x4*)(out_feat + slot0 * FEAT);
    const f32x4* src = (const f32x4*)st;
    #pragma unroll
    for (int k = t; k < 256 * FEAT / 4; k += 256)
        __builtin_nontemporal_store(src[k], &dst[k]);
}

// ---- Fallback gather (no stagedC) if d_ws is too small: round-8 form ----
__global__ __launch_bounds__(256) void select_kernel_nf(
    const int* __restrict__ cnt, const unsigned long long* __restrict__ buf,
    float* __restrict__ out_idx) {
    int v = blockIdx.x * blockDim.x + threadIdx.x;
    if (v >= NUM_VOXELS) return;
    unsigned long long top[KSLOTS];
    #pragma unroll
    for (int s = 0; s < KSLOTS; ++s) top[s] = 0ULL;
    int n = cnt[v];
    if (n > CAP) n = CAP;
    const unsigned long long* row = buf + (size_t)v * CAP;
    for (int j = 0; j < n; ++j) {
        unsigned long long key = row[j];
        #pragma unroll
        for (int s = 0; s < KSLOTS; ++s) {
            unsigned long long hi = key > top[s] ? key : top[s];
            unsigned long long lo = key > top[s] ? top[s] : key;
            top[s] = hi;
            key    = lo;
        }
    }
    float* o = out_idx + (size_t)v * KSLOTS;
    #pragma unroll
    for (int s = 0; s < KSLOTS; ++s) {
        unsigned long long k = top[s];
        o[s] = (float)((k != 0ULL) ? (int)(~(unsigned int)k) : -1);
    }
}

__global__ __launch_bounds__(256) void gather_kernel_nf(
    const float* __restrict__ pts, const float* __restrict__ conf,
    const float* __restrict__ desc, const float* __restrict__ desc_conf,
    const float* __restrict__ out_idx, float* __restrict__ out_feat) {
    const int t = threadIdx.x;
    const size_t slot0 = (size_t)blockIdx.x * 256;
    const size_t slot  = slot0 + t;
    __shared__ __align__(16) float st[256 * FEAT];
    int pid = (int)out_idx[slot];
    float f[FEAT];
    #pragma unroll
    for (int e = 0; e < FEAT; ++e) f[e] = 0.0f;
    if (pid >= 0) {
        f[0] = pts[(size_t)pid * 3 + 0];
        f[1] = pts[(size_t)pid * 3 + 1];
        f[2] = pts[(size_t)pid * 3 + 2];
        f[3] = conf[pid];
        const f32x4* d4 = (const f32x4*)(desc) + (size_t)pid * 6;
        #pragma unroll
        for (int q = 0; q < 6; ++q) {
            f32x4 d = d4[q];
            f[4 + q * 4 + 0] = d.x; f[4 + q * 4 + 1] = d.y;
            f[4 + q * 4 + 2] = d.z; f[4 + q * 4 + 3] = d.w;
        }
        f[28] = desc_conf[pid];
    }
    #pragma unroll
    for (int e = 0; e < FEAT; ++e) st[t * FEAT + e] = f[e];
    __syncthreads();
    f32x4* dst = (f32x4*)(out_feat + slot0 * FEAT);
    const f32x4* src = (const f32x4*)st;
    #pragma unroll
    for (int k = t; k < 256 * FEAT / 4; k += 256)
        __builtin_nontemporal_store(src[k], &dst[k]);
}

extern "C" void kernel_launch(void* const* d_in, const int* in_sizes, int n_in,
                              void* d_out, int out_size, void* d_ws, size_t ws_size,
                              hipStream_t stream) {
    const float* pts       = (const float*)d_in[0];
    const float* conf      = (const float*)d_in[1];
    const float* desc      = (const float*)d_in[2];
    const float* desc_conf = (const float*)d_in[3];
    const int n = in_sizes[1];  // conf is (N,)

    float* out_idx  = (float*)d_out;                         // (V,16) as float
    float* out_feat = out_idx + (size_t)NUM_VOXELS * KSLOTS; // (V,16,29)

    const size_t sz_cnt  = (size_t)NUM_VOXELS * 4;           // 1 MB
    const size_t sz_buf  = (size_t)NUM_VOXELS * CAP * 8;     // 64 MB
    const size_t sz_stgc = (size_t)NUM_VOXELS * KSLOTS * 4;  // 16 MB

    if (ws_size >= sz_cnt + sz_buf + sz_stgc) {
        int* cnt = (int*)d_ws;
        unsigned long long* buf = (unsigned long long*)((char*)d_ws + sz_cnt);
        float* stagedC = (float*)((char*)d_ws + sz_cnt + sz_buf);
        (void)hipMemsetAsync(cnt, 0, sz_cnt, stream);
        scatter_kernel<<<(n + 255) / 256, 256, 0, stream>>>(pts, conf, n, cnt, buf);
        select_kernel<<<NUM_VOXELS / 256, 256, 0, stream>>>(cnt, buf, out_idx, stagedC);
        gather_kernel<<<(NUM_VOXELS * KSLOTS) / 256, 256, 0, stream>>>(
            pts, stagedC, desc, desc_conf, out_idx, out_feat);
    } else {
        // Fallback: scratch at head of X region (rewritten by gather), no staging.
        int* cnt = (int*)out_feat;
        unsigned long long* buf = (unsigned long long*)(out_feat + NUM_VOXELS);
        (void)hipMemsetAsync(cnt, 0, sz_cnt, stream);
        scatter_kernel<<<(n + 255) / 256, 256, 0, stream>>>(pts, conf, n, cnt, buf);
        select_kernel_nf<<<NUM_VOXELS / 256, 256, 0, stream>>>(cnt, buf, out_idx);
        gather_kernel_nf<<<(NUM_VOXELS * KSLOTS) / 256, 256, 0, stream>>>(
            pts, conf, desc, desc_conf, out_idx, out_feat);
    }
}